// Round 1
// baseline (645.696 us; speedup 1.0000x reference)
//
#include <hip/hip_runtime.h>
#include <hip/hip_bf16.h>
#include <stdint.h>

#define T_TOK 1024
#define H_DIM 2048
#define NEXP 8
#define IED 1408
#define ISD 5632

typedef __attribute__((ext_vector_type(8))) short s16x8;
typedef __attribute__((ext_vector_type(8))) unsigned short u16x8;
typedef __attribute__((ext_vector_type(4))) float f32x4;

__device__ __forceinline__ unsigned short f2bf(float f) {
  union { float f; unsigned u; } v; v.f = f;
  unsigned r = v.u + 0x7FFFu + ((v.u >> 16) & 1u);
  return (unsigned short)(r >> 16);
}

__device__ __forceinline__ void gload16(const void* g, void* l) {
  __builtin_amdgcn_global_load_lds(
      (const __attribute__((address_space(1))) unsigned int*)g,
      (__attribute__((address_space(3))) unsigned int*)l, 16, 0, 0);
}

// ---------------- fp32 -> bf16 convert for hidden states ----------------
extern "C" __global__ void __launch_bounds__(256) k_cvt(
    const float* __restrict__ x, unsigned short* __restrict__ xb) {
  int i = (blockIdx.x * 256 + threadIdx.x) * 4;
  float4 v = *(const float4*)(x + i);
  ushort4 o;
  o.x = f2bf(v.x); o.y = f2bf(v.y); o.z = f2bf(v.z); o.w = f2bf(v.w);
  *(ushort4*)(xb + i) = o;
}

// ---------------- router: logits, softmax, top-4, shared gate ----------------
extern "C" __global__ void __launch_bounds__(256) k_router(
    const float* __restrict__ x, const float* __restrict__ wg,
    const float* __restrict__ wsg, int* __restrict__ counts,
    int* __restrict__ tlist, float* __restrict__ wlist,
    float* __restrict__ gate_sig) {
  const int lane = threadIdx.x & 63;
  const int t = blockIdx.x * 4 + (threadIdx.x >> 6);
  const float* xr = x + (size_t)t * H_DIM;
  float acc[8];
#pragma unroll
  for (int e = 0; e < 8; e++) acc[e] = 0.f;
  float sg = 0.f;
  for (int h = lane; h < H_DIM; h += 64) {
    float xv = xr[h];
    float4 w0 = *(const float4*)(wg + h * 8);
    float4 w1 = *(const float4*)(wg + h * 8 + 4);
    acc[0] += xv * w0.x; acc[1] += xv * w0.y; acc[2] += xv * w0.z; acc[3] += xv * w0.w;
    acc[4] += xv * w1.x; acc[5] += xv * w1.y; acc[6] += xv * w1.z; acc[7] += xv * w1.w;
    sg += xv * wsg[h];
  }
#pragma unroll
  for (int d = 32; d >= 1; d >>= 1) {
#pragma unroll
    for (int e = 0; e < 8; e++) acc[e] += __shfl_xor(acc[e], d, 64);
    sg += __shfl_xor(sg, d, 64);
  }
  if (lane == 0) {
    float m = acc[0];
#pragma unroll
    for (int e = 1; e < 8; e++) m = fmaxf(m, acc[e]);
    float p[8], s = 0.f;
#pragma unroll
    for (int e = 0; e < 8; e++) { p[e] = __expf(acc[e] - m); s += p[e]; }
    float inv = 1.f / s;
    bool used[8];
#pragma unroll
    for (int e = 0; e < 8; e++) used[e] = false;
    for (int j = 0; j < 4; j++) {
      int be = 0; float bv = -1e30f;
#pragma unroll
      for (int e = 0; e < 8; e++)
        if (!used[e] && acc[e] > bv) { bv = acc[e]; be = e; }
      used[be] = true;
      int slot = atomicAdd(counts + be, 1);
      tlist[be * T_TOK + slot] = t;
      wlist[be * T_TOK + slot] = p[be] * inv;
    }
    gate_sig[t] = 1.f / (1.f + __expf(-sg));
  }
}

// ---------------- unified MFMA GEMM ----------------
// MODE 0: shared gu   (A=xb [T,H],  B=w_shared_gu [H,2*ISD],  out act_s silu*mul)
// MODE 1: expert gu   (A=xb gathered, B=w_exp_gu[e], out act_e silu*mul*weight)
// MODE 2: shared down (A=act_s [T,ISD], B=w_shared_down, split-K by z, atomicAdd*sigmoid)
// MODE 3: expert down (A=act_e[e], B=w_exp_down[e], scatter atomicAdd)
template <int MODE>
__global__ void __launch_bounds__(256, 2) k_mm(
    const unsigned short* __restrict__ Abase, const float* __restrict__ Bbase,
    unsigned short* __restrict__ actout, float* __restrict__ out,
    const int* __restrict__ counts, const int* __restrict__ tlist,
    const float* __restrict__ wlist, const float* __restrict__ gate_sig) {
  const int tid = threadIdx.x;
  const int lane = tid & 63;
  const int wid = tid >> 6;
  const int wm = wid >> 1, wn = wid & 1;
  const int mtile = blockIdx.x, ntile = blockIdx.y, z = blockIdx.z;

  int e = -1, count = T_TOK, kbeg = 0, kend = 0, lda = 0, ldb = 0, IK = 0;
  const unsigned short* A = Abase;
  const float* B0 = nullptr; const float* B1 = nullptr;
  const int* tl = nullptr; const float* wl = nullptr;

  if constexpr (MODE == 0) {
    lda = H_DIM; kend = H_DIM; ldb = 2 * ISD; IK = ISD;
    B0 = Bbase + ntile * 64; B1 = Bbase + ISD + ntile * 64;
  } else if constexpr (MODE == 1) {
    e = z; count = counts[e];
    if (mtile * 128 >= count) return;
    lda = H_DIM; kend = H_DIM; ldb = 2 * IED; IK = IED;
    const float* Bw = Bbase + (size_t)e * H_DIM * (2 * IED);
    B0 = Bw + ntile * 64; B1 = Bw + IED + ntile * 64;
    tl = tlist + e * T_TOK; wl = wlist + e * T_TOK;
    actout += (size_t)e * T_TOK * IED;
  } else if constexpr (MODE == 2) {
    lda = ISD; kbeg = z * 1408; kend = kbeg + 1408; ldb = H_DIM; IK = H_DIM;
    B0 = Bbase + ntile * 128; B1 = Bbase + ntile * 128 + 64;
  } else {
    e = z; count = counts[e];
    if (mtile * 128 >= count) return;
    lda = IED; kend = IED; ldb = H_DIM; IK = H_DIM;
    B0 = Bbase + (size_t)e * IED * H_DIM + ntile * 128;
    B1 = B0 + 64;
    A = Abase + (size_t)e * T_TOK * IED;
    tl = tlist + e * T_TOK;
  }

  __shared__ unsigned short a_lds[128 * 64];  // [row][swizzled 8-elem chunk]
  __shared__ unsigned short b_lds[128 * 64];  // Bt[n][k] swizzled

  // A staging: 4 global_load_lds calls/thread, pre-swizzled source addresses.
  const unsigned short* asrc[4];
  unsigned short* adst[4];
  {
    int kc = (lane & 7) ^ ((lane >> 3) & 7);
#pragma unroll
    for (int q = 0; q < 4; q++) {
      int row = wid * 32 + q * 8 + (lane >> 3);
      int rowg = mtile * 128 + row;
      int arow = rowg;
      if constexpr (MODE == 1) arow = tl[rowg];
      asrc[q] = A + (size_t)arow * lda + kc * 8;
      adst[q] = &a_lds[(wid * 4 + q) * 512];
    }
  }

  // B staging geometry: thread covers n = bn, bn+1 (per half) x k = bkset..bkset+7
  const int bn = (tid & 31) * 2;
  const int bkset = ((tid >> 5) & 7) * 8;
  const int bkc = (tid >> 5) & 7;
  unsigned short* bwr[2][2];
#pragma unroll
  for (int h = 0; h < 2; h++)
#pragma unroll
    for (int j = 0; j < 2; j++) {
      int r = h * 64 + bn + j;
      bwr[h][j] = &b_lds[r * 64 + ((bkc ^ (r & 7)) * 8)];
    }

  const f32x4 fzero = {0.f, 0.f, 0.f, 0.f};
  f32x4 acc[4][4];
#pragma unroll
  for (int m = 0; m < 4; m++)
#pragma unroll
    for (int n = 0; n < 4; n++) acc[m][n] = fzero;

  for (int k0 = kbeg; k0 < kend; k0 += 64) {
    __syncthreads();
#pragma unroll
    for (int q = 0; q < 4; q++) gload16(asrc[q] + k0, adst[q]);
    float2 vg[8], vu[8];
#pragma unroll
    for (int i = 0; i < 8; i++) {
      size_t ko = (size_t)(k0 + bkset + i) * (size_t)ldb;
      vg[i] = *(const float2*)(B0 + ko + bn);
      vu[i] = *(const float2*)(B1 + ko + bn);
    }
#pragma unroll
    for (int j = 0; j < 2; j++) {
      u16x8 pg, pu;
#pragma unroll
      for (int i = 0; i < 8; i++) {
        pg[i] = f2bf(j ? vg[i].y : vg[i].x);
        pu[i] = f2bf(j ? vu[i].y : vu[i].x);
      }
      *(u16x8*)bwr[0][j] = pg;
      *(u16x8*)bwr[1][j] = pu;
    }
    __syncthreads();
#pragma unroll
    for (int ks = 0; ks < 2; ks++) {
      int kc = ks * 4 + (lane >> 4);
      s16x8 a[4];
#pragma unroll
      for (int m = 0; m < 4; m++) {
        int r = wm * 64 + m * 16 + (lane & 15);
        a[m] = *(const s16x8*)&a_lds[r * 64 + ((kc ^ (r & 7)) * 8)];
      }
#pragma unroll
      for (int nf = 0; nf < 4; nf++) {
        int rb;
        if constexpr (MODE < 2) rb = wn * 32 + (nf & 1) * 16 + (nf >> 1) * 64;
        else rb = wn * 64 + nf * 16;
        rb += (lane & 15);
        s16x8 b = *(const s16x8*)&b_lds[rb * 64 + ((kc ^ (rb & 7)) * 8)];
#pragma unroll
        for (int m = 0; m < 4; m++)
          acc[m][nf] = __builtin_amdgcn_mfma_f32_16x16x32_bf16(a[m], b, acc[m][nf], 0, 0, 0);
      }
    }
  }

  if constexpr (MODE < 2) {
#pragma unroll
    for (int m = 0; m < 4; m++) {
#pragma unroll
      for (int i = 0; i < 4; i++) {
        int rowslot = mtile * 128 + wm * 64 + m * 16 + (lane >> 4) * 4 + i;
        float rsc = 1.f;
        if constexpr (MODE == 1) rsc = wl[rowslot];
#pragma unroll
        for (int p = 0; p < 2; p++) {
          float g = acc[m][p][i];
          float u = acc[m][p + 2][i];
          float sv = g / (1.f + __expf(-g)) * u * rsc;
          int col = ntile * 64 + wn * 32 + p * 16 + (lane & 15);
          actout[(size_t)rowslot * IK + col] = f2bf(sv);
        }
      }
    }
  } else {
#pragma unroll
    for (int m = 0; m < 4; m++) {
#pragma unroll
      for (int i = 0; i < 4; i++) {
        int rowslot = mtile * 128 + wm * 64 + m * 16 + (lane >> 4) * 4 + i;
        int token = rowslot;
        if constexpr (MODE == 3) token = tl[rowslot];
        float sc = 1.f;
        if constexpr (MODE == 2) sc = gate_sig[token];
        float* orow = out + (size_t)token * H_DIM + ntile * 128 + wn * 64 + (lane & 15);
#pragma unroll
        for (int nf = 0; nf < 4; nf++)
          atomicAdd(orow + nf * 16, acc[m][nf][i] * sc);
      }
    }
  }
}

extern "C" void kernel_launch(void* const* d_in, const int* in_sizes, int n_in,
                              void* d_out, int out_size, void* d_ws, size_t ws_size,
                              hipStream_t stream) {
  (void)in_sizes; (void)n_in; (void)out_size; (void)ws_size;
  const float* x    = (const float*)d_in[0];
  const float* wg   = (const float*)d_in[1];
  const float* wsg  = (const float*)d_in[2];
  const float* wsgu = (const float*)d_in[3];
  const float* wsd  = (const float*)d_in[4];
  const float* wegu = (const float*)d_in[5];
  const float* wed  = (const float*)d_in[6];
  float* out = (float*)d_out;

  char* ws = (char*)d_ws;
  unsigned short* xb   = (unsigned short*)ws;                                   // 4 MB
  unsigned short* acts = (unsigned short*)(ws + (4u << 20));                    // T*ISD bf16
  unsigned short* acte = (unsigned short*)(ws + (4u << 20) + 11534336u);        // E*T*IED bf16
  char* ctrl = ws + (4u << 20) + 11534336u + 23068672u;
  int* counts    = (int*)ctrl;
  int* tlist     = (int*)(ctrl + 256);
  float* wlist   = (float*)(ctrl + 256 + 32768);
  float* gate_sig = (float*)(ctrl + 256 + 65536);

  hipMemsetAsync(d_out, 0, (size_t)T_TOK * H_DIM * 4, stream);
  hipMemsetAsync(ctrl, 0, 256 + 65536, stream);

  k_cvt<<<dim3(2048), dim3(256), 0, stream>>>(x, xb);
  k_router<<<dim3(256), dim3(256), 0, stream>>>(x, wg, wsg, counts, tlist, wlist, gate_sig);
  k_mm<0><<<dim3(8, 88), dim3(256), 0, stream>>>(xb, wsgu, acts, out, counts, tlist, wlist, gate_sig);
  k_mm<1><<<dim3(8, 22, 8), dim3(256), 0, stream>>>(xb, wegu, acte, out, counts, tlist, wlist, gate_sig);
  k_mm<2><<<dim3(8, 16, 4), dim3(256), 0, stream>>>(acts, wsd, nullptr, out, counts, tlist, wlist, gate_sig);
  k_mm<3><<<dim3(8, 16, 8), dim3(256), 0, stream>>>(acte, wed, nullptr, out, counts, tlist, wlist, gate_sig);
}

// Round 2
// 610.771 us; speedup vs baseline: 1.0572x; 1.0572x over previous
//
#include <hip/hip_runtime.h>
#include <hip/hip_bf16.h>
#include <stdint.h>

#define T_TOK 1024
#define H_DIM 2048
#define NEXP 8
#define IED 1408
#define ISD 5632

typedef __attribute__((ext_vector_type(8))) short s16x8;
typedef __attribute__((ext_vector_type(8))) unsigned short u16x8;
typedef __attribute__((ext_vector_type(4))) float f32x4;

__device__ __forceinline__ unsigned short f2bf(float f) {
  union { float f; unsigned u; } v; v.f = f;
  unsigned r = v.u + 0x7FFFu + ((v.u >> 16) & 1u);
  return (unsigned short)(r >> 16);
}

__device__ __forceinline__ void gload16(const void* g, void* l) {
  __builtin_amdgcn_global_load_lds(
      (const __attribute__((address_space(1))) unsigned int*)g,
      (__attribute__((address_space(3))) unsigned int*)l, 16, 0, 0);
}

// ---------------- fp32 -> bf16 convert for hidden states ----------------
extern "C" __global__ void __launch_bounds__(256) k_cvt(
    const float* __restrict__ x, unsigned short* __restrict__ xb) {
  int i = (blockIdx.x * 256 + threadIdx.x) * 4;
  float4 v = *(const float4*)(x + i);
  ushort4 o;
  o.x = f2bf(v.x); o.y = f2bf(v.y); o.z = f2bf(v.z); o.w = f2bf(v.w);
  *(ushort4*)(xb + i) = o;
}

// ---------------- router: logits, softmax, top-4, shared gate ----------------
extern "C" __global__ void __launch_bounds__(256) k_router(
    const float* __restrict__ x, const float* __restrict__ wg,
    const float* __restrict__ wsg, int* __restrict__ counts,
    int* __restrict__ tlist, float* __restrict__ wlist,
    float* __restrict__ gate_sig) {
  const int lane = threadIdx.x & 63;
  const int t = blockIdx.x * 4 + (threadIdx.x >> 6);
  const float* xr = x + (size_t)t * H_DIM;
  float acc[8];
#pragma unroll
  for (int e = 0; e < 8; e++) acc[e] = 0.f;
  float sg = 0.f;
  for (int h = lane; h < H_DIM; h += 64) {
    float xv = xr[h];
    float4 w0 = *(const float4*)(wg + h * 8);
    float4 w1 = *(const float4*)(wg + h * 8 + 4);
    acc[0] += xv * w0.x; acc[1] += xv * w0.y; acc[2] += xv * w0.z; acc[3] += xv * w0.w;
    acc[4] += xv * w1.x; acc[5] += xv * w1.y; acc[6] += xv * w1.z; acc[7] += xv * w1.w;
    sg += xv * wsg[h];
  }
#pragma unroll
  for (int d = 32; d >= 1; d >>= 1) {
#pragma unroll
    for (int e = 0; e < 8; e++) acc[e] += __shfl_xor(acc[e], d, 64);
    sg += __shfl_xor(sg, d, 64);
  }
  if (lane == 0) {
    float m = acc[0];
#pragma unroll
    for (int e = 1; e < 8; e++) m = fmaxf(m, acc[e]);
    float p[8], s = 0.f;
#pragma unroll
    for (int e = 0; e < 8; e++) { p[e] = __expf(acc[e] - m); s += p[e]; }
    float inv = 1.f / s;
    bool used[8];
#pragma unroll
    for (int e = 0; e < 8; e++) used[e] = false;
    for (int j = 0; j < 4; j++) {
      int be = 0; float bv = -1e30f;
#pragma unroll
      for (int e = 0; e < 8; e++)
        if (!used[e] && acc[e] > bv) { bv = acc[e]; be = e; }
      used[be] = true;
      int slot = atomicAdd(counts + be, 1);
      tlist[be * T_TOK + slot] = t;
      wlist[be * T_TOK + slot] = p[be] * inv;
    }
    gate_sig[t] = 1.f / (1.f + __expf(-sg));
  }
}

// ---------------- unified MFMA GEMM, 2-phase pipelined, XCD-grouped ----------------
// MODE 0: shared gu   (A=xb [T,H],  B=w_shared_gu [H,2*ISD],  out act_s silu*mul)
// MODE 1: expert gu   (A=xb gathered, B=w_exp_gu[e], out act_e silu*mul*weight)
// MODE 2: shared down (A=act_s [T,ISD], B=w_shared_down, split-K by z, atomicAdd*sigmoid)
// MODE 3: expert down (A=act_e[e], B=w_exp_down[e], scatter atomicAdd)
template <int MODE>
__global__ void __launch_bounds__(256, 2) k_mm(
    const unsigned short* __restrict__ Abase, const float* __restrict__ Bbase,
    unsigned short* __restrict__ actout, float* __restrict__ out,
    const int* __restrict__ counts, const int* __restrict__ tlist,
    const float* __restrict__ wlist, const float* __restrict__ gate_sig) {
  const int tid = threadIdx.x;
  const int lane = tid & 63;
  const int wid = tid >> 6;
  const int wm = wid >> 1, wn = wid & 1;

  // XCD-grouped decode: xcd = b%8 owns P/8 consecutive B-panels; mtile fastest.
  constexpr int P = (MODE == 0) ? 88 : (MODE == 1) ? 176 : (MODE == 2) ? 64 : 128;
  const int b = blockIdx.x;
  const int xcd = b & 7;
  const int j = b >> 3;
  const int panel = xcd * (P >> 3) + (j >> 3);
  const int mtile = j & 7;
  int ntile = 0, z = 0, e = 0;
  if constexpr (MODE == 0) { ntile = panel; }
  else if constexpr (MODE == 1) { e = panel & 7; ntile = panel >> 3; }
  else if constexpr (MODE == 2) { ntile = panel >> 2; z = panel & 3; }
  else { e = panel & 7; ntile = panel >> 3; }

  int count = T_TOK, kbeg = 0, kend = 0, lda = 0, ldb = 0, IK = 0;
  const unsigned short* A = Abase;
  const float* B0 = nullptr; const float* B1 = nullptr;
  const int* tl = nullptr; const float* wl = nullptr;

  if constexpr (MODE == 0) {
    lda = H_DIM; kend = H_DIM; ldb = 2 * ISD; IK = ISD;
    B0 = Bbase + ntile * 64; B1 = Bbase + ISD + ntile * 64;
  } else if constexpr (MODE == 1) {
    count = counts[e];
    if (mtile * 128 >= count) return;
    lda = H_DIM; kend = H_DIM; ldb = 2 * IED; IK = IED;
    const float* Bw = Bbase + (size_t)e * H_DIM * (2 * IED);
    B0 = Bw + ntile * 64; B1 = Bw + IED + ntile * 64;
    tl = tlist + e * T_TOK; wl = wlist + e * T_TOK;
    actout += (size_t)e * T_TOK * IED;
  } else if constexpr (MODE == 2) {
    lda = ISD; kbeg = z * 1408; kend = kbeg + 1408; ldb = H_DIM; IK = H_DIM;
    B0 = Bbase + ntile * 128; B1 = Bbase + ntile * 128 + 64;
  } else {
    count = counts[e];
    if (mtile * 128 >= count) return;
    lda = IED; kend = IED; ldb = H_DIM; IK = H_DIM;
    B0 = Bbase + (size_t)e * IED * H_DIM + ntile * 128;
    B1 = B0 + 64;
    A = Abase + (size_t)e * T_TOK * IED;
    tl = tlist + e * T_TOK;
  }

  __shared__ unsigned short a_lds[2 * 8192];  // [buf][row][swizzled 8-elem chunk]
  __shared__ unsigned short b_lds[2 * 8192];  // [buf] Bt[n][k] swizzled

  // A staging: 4 global_load_lds calls/thread, pre-swizzled source addresses.
  const unsigned short* asrc[4];
  unsigned short* adst[4];
  {
    int kc = (lane & 7) ^ ((lane >> 3) & 7);
#pragma unroll
    for (int q = 0; q < 4; q++) {
      int row = wid * 32 + q * 8 + (lane >> 3);
      int rowg = mtile * 128 + row;
      int arow = rowg;
      if constexpr (MODE == 1) arow = tl[rowg];  // padding slots hold 0 (memset)
      asrc[q] = A + (size_t)arow * lda + kc * 8;
      adst[q] = &a_lds[(wid * 4 + q) * 512];
    }
  }

  // B staging geometry: thread covers n = bn, bn+1 (per half) x k = bkset..bkset+7
  const int bn = (tid & 31) * 2;
  const int bkset = ((tid >> 5) & 7) * 8;
  const int bkc = (tid >> 5) & 7;
  unsigned short* bwr[2][2];
#pragma unroll
  for (int h = 0; h < 2; h++)
#pragma unroll
    for (int jj = 0; jj < 2; jj++) {
      int r = h * 64 + bn + jj;
      bwr[h][jj] = &b_lds[r * 64 + ((bkc ^ (r & 7)) * 8)];
    }

  const f32x4 fzero = {0.f, 0.f, 0.f, 0.f};
  f32x4 acc[4][4];
#pragma unroll
  for (int m = 0; m < 4; m++)
#pragma unroll
    for (int n = 0; n < 4; n++) acc[m][n] = fzero;

  const int nt = (kend - kbeg) >> 6;
  float2 vg[8], vu[8];

  // ---- prologue: stage tile 0 into buf 0 ----
#pragma unroll
  for (int q = 0; q < 4; q++) gload16(asrc[q] + kbeg, adst[q]);
#pragma unroll
  for (int i = 0; i < 8; i++) {
    size_t ko = (size_t)(kbeg + bkset + i) * (size_t)ldb;
    vg[i] = *(const float2*)(B0 + ko + bn);
    vu[i] = *(const float2*)(B1 + ko + bn);
  }
#pragma unroll
  for (int jj = 0; jj < 2; jj++) {
    u16x8 pg, pu;
#pragma unroll
    for (int i = 0; i < 8; i++) {
      pg[i] = f2bf(jj ? vg[i].y : vg[i].x);
      pu[i] = f2bf(jj ? vu[i].y : vu[i].x);
    }
    *(u16x8*)bwr[0][jj] = pg;
    *(u16x8*)bwr[1][jj] = pu;
  }
  __syncthreads();

  for (int t = 0; t < nt; ++t) {
    const int cur = t & 1;
    const int curoff = cur * 8192;
    const int nxtoff = (cur ^ 1) * 8192;
    const int k0 = kbeg + t * 64;
    const bool more = (t + 1 < nt);
    // ---- issue next tile's loads (A -> LDS DMA, B -> regs) ----
    if (more) {
#pragma unroll
      for (int q = 0; q < 4; q++) gload16(asrc[q] + k0 + 64, adst[q] + nxtoff);
#pragma unroll
      for (int i = 0; i < 8; i++) {
        size_t ko = (size_t)(k0 + 64 + bkset + i) * (size_t)ldb;
        vg[i] = *(const float2*)(B0 + ko + bn);
        vu[i] = *(const float2*)(B1 + ko + bn);
      }
    }
    // ---- compute current tile ----
    const unsigned short* ab = a_lds + curoff;
    const unsigned short* bb = b_lds + curoff;
#pragma unroll
    for (int ks = 0; ks < 2; ks++) {
      int kc = ks * 4 + (lane >> 4);
      s16x8 a[4];
#pragma unroll
      for (int m = 0; m < 4; m++) {
        int r = wm * 64 + m * 16 + (lane & 15);
        a[m] = *(const s16x8*)&ab[r * 64 + ((kc ^ (r & 7)) * 8)];
      }
#pragma unroll
      for (int nf = 0; nf < 4; nf++) {
        int rb;
        if constexpr (MODE < 2) rb = wn * 32 + (nf & 1) * 16 + (nf >> 1) * 64;
        else rb = wn * 64 + nf * 16;
        rb += (lane & 15);
        s16x8 bfr = *(const s16x8*)&bb[rb * 64 + ((kc ^ (rb & 7)) * 8)];
#pragma unroll
        for (int m = 0; m < 4; m++)
          acc[m][nf] = __builtin_amdgcn_mfma_f32_16x16x32_bf16(a[m], bfr, acc[m][nf], 0, 0, 0);
      }
    }
    // ---- convert + write next tile's B into other buffer ----
    if (more) {
#pragma unroll
      for (int jj = 0; jj < 2; jj++) {
        u16x8 pg, pu;
#pragma unroll
        for (int i = 0; i < 8; i++) {
          pg[i] = f2bf(jj ? vg[i].y : vg[i].x);
          pu[i] = f2bf(jj ? vu[i].y : vu[i].x);
        }
        *(u16x8*)(bwr[0][jj] + nxtoff) = pg;
        *(u16x8*)(bwr[1][jj] + nxtoff) = pu;
      }
    }
    __syncthreads();
  }

  if constexpr (MODE < 2) {
#pragma unroll
    for (int m = 0; m < 4; m++) {
#pragma unroll
      for (int i = 0; i < 4; i++) {
        int rowslot = mtile * 128 + wm * 64 + m * 16 + (lane >> 4) * 4 + i;
        float rsc = 1.f;
        if constexpr (MODE == 1) rsc = wl[rowslot];  // padding slots: 0.0 (memset)
#pragma unroll
        for (int p = 0; p < 2; p++) {
          float g = acc[m][p][i];
          float u = acc[m][p + 2][i];
          float sv = g / (1.f + __expf(-g)) * u * rsc;
          int col = ntile * 64 + wn * 32 + p * 16 + (lane & 15);
          actout[(size_t)rowslot * IK + col] = f2bf(sv);
        }
      }
    }
  } else {
#pragma unroll
    for (int m = 0; m < 4; m++) {
#pragma unroll
      for (int i = 0; i < 4; i++) {
        int rowslot = mtile * 128 + wm * 64 + m * 16 + (lane >> 4) * 4 + i;
        int token = rowslot;
        if constexpr (MODE == 3) token = tl[rowslot];  // padding: token 0, acc==0
        float sc = 1.f;
        if constexpr (MODE == 2) sc = gate_sig[token];
        float* orow = out + (size_t)token * H_DIM + ntile * 128 + wn * 64 + (lane & 15);
#pragma unroll
        for (int nf = 0; nf < 4; nf++)
          atomicAdd(orow + nf * 16, acc[m][nf][i] * sc);
      }
    }
  }
}

extern "C" void kernel_launch(void* const* d_in, const int* in_sizes, int n_in,
                              void* d_out, int out_size, void* d_ws, size_t ws_size,
                              hipStream_t stream) {
  (void)in_sizes; (void)n_in; (void)out_size; (void)ws_size;
  const float* x    = (const float*)d_in[0];
  const float* wg   = (const float*)d_in[1];
  const float* wsg  = (const float*)d_in[2];
  const float* wsgu = (const float*)d_in[3];
  const float* wsd  = (const float*)d_in[4];
  const float* wegu = (const float*)d_in[5];
  const float* wed  = (const float*)d_in[6];
  float* out = (float*)d_out;

  char* ws = (char*)d_ws;
  unsigned short* xb   = (unsigned short*)ws;                                   // 4 MB
  unsigned short* acts = (unsigned short*)(ws + (4u << 20));                    // T*ISD bf16
  unsigned short* acte = (unsigned short*)(ws + (4u << 20) + 11534336u);        // E*T*IED bf16
  char* ctrl = ws + (4u << 20) + 11534336u + 23068672u;
  int* counts    = (int*)ctrl;
  int* tlist     = (int*)(ctrl + 256);
  float* wlist   = (float*)(ctrl + 256 + 32768);
  float* gate_sig = (float*)(ctrl + 256 + 65536);

  hipMemsetAsync(d_out, 0, (size_t)T_TOK * H_DIM * 4, stream);
  hipMemsetAsync(ctrl, 0, 256 + 65536, stream);

  k_cvt<<<dim3(2048), dim3(256), 0, stream>>>(x, xb);
  k_router<<<dim3(256), dim3(256), 0, stream>>>(x, wg, wsg, counts, tlist, wlist, gate_sig);
  k_mm<0><<<dim3(704), dim3(256), 0, stream>>>(xb, wsgu, acts, out, counts, tlist, wlist, gate_sig);
  k_mm<1><<<dim3(1408), dim3(256), 0, stream>>>(xb, wegu, acte, out, counts, tlist, wlist, gate_sig);
  k_mm<2><<<dim3(512), dim3(256), 0, stream>>>(acts, wsd, nullptr, out, counts, tlist, wlist, gate_sig);
  k_mm<3><<<dim3(1024), dim3(256), 0, stream>>>(acte, wed, nullptr, out, counts, tlist, wlist, gate_sig);
}